// Round 1
// baseline (515.121 us; speedup 1.0000x reference)
//
#include <hip/hip_runtime.h>

// SubGroupPooler: Z[t, s*D + d] = max_{g in team s} P[idx[s][g], t, d]
// N=12 players, T=4096 frames, D=2048 dims, 2 teams x 6 players.
// Memory-bound: 402.7 MB read + 67.1 MB write -> ~75-90 us floor at 6.3 TB/s.
//
// R4: team-split grid (T, 2). Each block handles one (frame, team) pair:
// 256 threads x 2 float4 columns (d4 = k*256+tid, k=0..1), 12 independent
// nontemporal dwordx4 loads per thread (6 players x 2 halves). Halves
// per-thread register state vs the 24-load version (R2/R3) -> ~4 waves/SIMD
// instead of ~2, 2x resident blocks, same fully-coalesced traffic.
// Per-player fx4 base offsets hoisted once; d4 is the only per-lane term.
// nt load/store policy retained from R2/R3 (zero reuse, input > L3).

constexpr int T_FRAMES = 4096;
constexpr int D_DIM    = 2048;

typedef float  fx4 __attribute__((ext_vector_type(4)));
typedef int    ix4 __attribute__((ext_vector_type(4)));

__global__ __launch_bounds__(256) void SubGroupPooler_59708635349141_kernel(
    const float* __restrict__ P,     // [12, T, D]
    const int*   __restrict__ idx,   // [2, 6] (int32 or int64 -- detected)
    float*       __restrict__ out)   // [T, 2*D]
{
    constexpr int D4  = D_DIM / 4;           // 512 fx4 per player-row
    constexpr int Z4  = 2 * D4;              // 1024 fx4 per output row
    constexpr int TD4 = T_FRAMES * D4;       // fx4 per player slab (2^21)

    const int t   = blockIdx.x;              // frame
    const int s   = blockIdx.y;              // team 0/1
    const int tid = threadIdx.x;

    // Load this team's 6 indices with wide loads. int64 detection: LE int64
    // view of arange has ints (0,0,1,0,...) -> y==w==0; int32 view (0,1,2,3)
    // doesn't. Wave-uniform branches only.
    const ix4* idx4 = (const ix4*)idx;
    int p[6];
    {
        ix4 a = idx4[0];
        if (a.y == 0 && a.w == 0) {          // int64: value e at int 2e
            ix4 x0 = idx4[3 * s + 0];
            ix4 x1 = idx4[3 * s + 1];
            ix4 x2 = idx4[3 * s + 2];
            p[0] = x0.x; p[1] = x0.z;
            p[2] = x1.x; p[3] = x1.z;
            p[4] = x2.x; p[5] = x2.z;
        } else {                             // int32 layout
            ix4 b = idx4[1], c = idx4[2];
            if (s == 0) {
                p[0] = a.x; p[1] = a.y; p[2] = a.z;
                p[3] = a.w; p[4] = b.x; p[5] = b.y;
            } else {
                p[0] = b.z; p[1] = b.w; p[2] = c.x;
                p[3] = c.y; p[4] = c.z; p[5] = c.w;
            }
        }
    }

    const fx4* __restrict__ P4   = (const fx4*)P;
    fx4*       __restrict__ out4 = (fx4*)out;
    const int rowbase = t * D4;

    // Per-player fx4 base offset for row t (static indices -> registers).
    size_t base[6];
    #pragma unroll
    for (int g = 0; g < 6; ++g)
        base[g] = (size_t)p[g] * TD4 + rowbase;

    #pragma unroll
    for (int k = 0; k < 2; ++k) {
        const int d4 = k * 256 + tid;        // column within this team's block

        fx4 m = __builtin_nontemporal_load(&P4[base[0] + d4]);
        #pragma unroll
        for (int g = 1; g < 6; ++g) {
            fx4 v = __builtin_nontemporal_load(&P4[base[g] + d4]);
            m.x = fmaxf(m.x, v.x);
            m.y = fmaxf(m.y, v.y);
            m.z = fmaxf(m.z, v.z);
            m.w = fmaxf(m.w, v.w);
        }
        __builtin_nontemporal_store(
            m, &out4[(size_t)t * Z4 + s * D4 + d4]);
    }
}

extern "C" void kernel_launch(void* const* d_in, const int* in_sizes, int n_in,
                              void* d_out, int out_size, void* d_ws, size_t ws_size,
                              hipStream_t stream) {
    const float* P   = (const float*)d_in[0];
    const int*   idx = (const int*)d_in[1];
    float*       out = (float*)d_out;

    dim3 grid(T_FRAMES, 2);
    SubGroupPooler_59708635349141_kernel<<<grid, 256, 0, stream>>>(P, idx, out);
}